// Round 4
// baseline (277.475 us; speedup 1.0000x reference)
//
#include <hip/hip_runtime.h>
#include <math.h>

// Problem constants (fixed by the reference)
constexpr int Bn  = 32;
constexpr int Cn  = 256;
constexpr int Hn  = 64;
constexpr int Wn  = 64;
constexpr int HW  = Hn * Wn;        // 4096
constexpr int CHW = Cn * HW;        // 1048576
constexpr int HW4 = HW / 4;         // 1024 float4 per (b,c) plane
constexpr int NPOS  = Bn * HW;      // 131072 spatial positions
constexpr int NPOS4 = NPOS / 4;     // 32768 float4 positions

// convmul tiling: block = (batch b, 16-row stripe, 16-channel group)
constexpr int ROWS   = 16;                   // rows per stripe
constexpr int NSTR   = Hn / ROWS;            // 4 stripes
constexpr int CGRP   = 16;                   // channels per block
constexpr int NCG    = Cn / CGRP;            // 16 channel groups
constexpr int HALO   = 3;                    // 7x7 pad
constexpr int LROWS  = ROWS + 2 * HALO;      // 22 LDS rows (with halo)

// -------------------------------------------------------------------------
// Kernel 1: channel-wise max + mean.  (round-0 version, verbatim: part of
// the measured-best 89us config. Round-3's 512-thread variant regressed.)
// Block = 256 threads = 4 waves. Wave `chunk` reduces channels
// [chunk*64, chunk*64+64) for 64 consecutive float4 spatial positions.
// Each load: 64 lanes x 16 B contiguous = 1 KiB coalesced.
// NOTE: cooperative grid.sync fusion was tried (rounds 1-2) and is
// structurally dead on MI355X: sync spin costs ~70-250us/barrier, scaling
// with block count (cross-XCD device-scope polling). Separate dispatches
// win; L3 keeps x (134 MB < 256 MB) resident between kernel 1 and 2.
// -------------------------------------------------------------------------
__global__ __launch_bounds__(256) void reduce_k(const float* __restrict__ x,
                                                float* __restrict__ pmax,
                                                float* __restrict__ pavg) {
    __shared__ float4 smax[4][64];
    __shared__ float4 ssum[4][64];

    const int lane  = threadIdx.x & 63;
    const int chunk = threadIdx.x >> 6;           // 0..3 (wave id)
    const int pos4  = blockIdx.x * 64 + lane;     // global float4 position
    const int b     = pos4 >> 10;                 // / HW4 (block never straddles b)
    const int sp4   = pos4 & (HW4 - 1);

    const float4* xp = (const float4*)x + (size_t)b * (CHW / 4)
                       + (size_t)(chunk * 64) * HW4 + sp4;

    float4 mx = make_float4(-INFINITY, -INFINITY, -INFINITY, -INFINITY);
    float4 sm = make_float4(0.f, 0.f, 0.f, 0.f);

    #pragma unroll 8
    for (int c = 0; c < 64; ++c) {
        float4 v = xp[(size_t)c * HW4];
        mx.x = fmaxf(mx.x, v.x); mx.y = fmaxf(mx.y, v.y);
        mx.z = fmaxf(mx.z, v.z); mx.w = fmaxf(mx.w, v.w);
        sm.x += v.x; sm.y += v.y; sm.z += v.z; sm.w += v.w;
    }

    smax[chunk][lane] = mx;
    ssum[chunk][lane] = sm;
    __syncthreads();

    if (chunk == 0) {
        float4 M = smax[0][lane];
        float4 S = ssum[0][lane];
        #pragma unroll
        for (int k = 1; k < 4; ++k) {
            float4 m2 = smax[k][lane];
            float4 s2 = ssum[k][lane];
            M.x = fmaxf(M.x, m2.x); M.y = fmaxf(M.y, m2.y);
            M.z = fmaxf(M.z, m2.z); M.w = fmaxf(M.w, m2.w);
            S.x += s2.x; S.y += s2.y; S.z += s2.z; S.w += s2.w;
        }
        const float inv = 1.0f / (float)Cn;
        float4 A = make_float4(S.x * inv, S.y * inv, S.z * inv, S.w * inv);
        ((float4*)pmax)[pos4] = M;
        ((float4*)pavg)[pos4] = A;
    }
}

// -------------------------------------------------------------------------
// Kernel 2: fused 7x7 conv + sigmoid + broadcast multiply.
// Block = (b, stripe, channel-group): computes its 16x64 scale stripe from
// pmax/pavg (LDS, with 3-row halo; conv redundantly recomputed per channel
// group -- ~100 FLOP/position, negligible), then multiplies 16 channels.
// Removes the separate conv dispatch + the scale global round-trip; scale
// is a register operand in the multiply loop.
// 2048 blocks x 256 thr, LDS 15.7 KB -> 8 blocks/CU = 32 waves/CU.
// -------------------------------------------------------------------------
__global__ __launch_bounds__(256, 8) void convmul_k(const float* __restrict__ x,
                                                    const float* __restrict__ pmax,
                                                    const float* __restrict__ pavg,
                                                    const float* __restrict__ w,
                                                    float* __restrict__ out) {
    __shared__ float spm[LROWS * Wn];     // 22x64 pooled-max with halo
    __shared__ float spa[LROWS * Wn];     // 22x64 pooled-avg with halo
    __shared__ float ssc[ROWS * Wn];      // 16x64 scale stripe
    __shared__ float sw[98];

    const int tid = threadIdx.x;
    const int bid = blockIdx.x;
    const int cg     = bid & (NCG - 1);          // 0..15 channel group
    const int stripe = (bid >> 4) & (NSTR - 1);  // 0..3
    const int b      = bid >> 6;                 // 0..31
    const int r0     = stripe * ROWS;            // first output row

    if (tid < 98) sw[tid] = w[tid];

    // Stage pooled stripe + halo (rows r0-3 .. r0+18; out-of-range -> 0).
    const float* pm = pmax + b * HW;
    const float* pa = pavg + b * HW;
    for (int i = tid; i < LROWS * Wn; i += 256) {
        const int lr  = i >> 6;                  // 0..21
        const int col = i & 63;
        const int gh  = r0 - HALO + lr;
        const bool ok = (gh >= 0) && (gh < Hn);
        spm[i] = ok ? pm[gh * Wn + col] : 0.f;
        spa[i] = ok ? pa[gh * Wn + col] : 0.f;
    }
    __syncthreads();

    // Conv + sigmoid for the 16x64 stripe. Thread t does positions
    // t, t+256, t+512, t+768 (4 each). Row bounds pre-zeroed in LDS;
    // column bounds checked (zero pad).
    #pragma unroll
    for (int p = tid; p < ROWS * Wn; p += 256) {
        const int hl  = p >> 6;                  // local output row 0..15
        const int col = p & 63;
        float acc = 0.f;
        #pragma unroll
        for (int kh = 0; kh < 7; ++kh) {
            const int lr = hl + kh;              // LDS row (halo-shifted)
            #pragma unroll
            for (int kw = 0; kw < 7; ++kw) {
                const int ww = col + kw - 3;
                if (ww < 0 || ww >= Wn) continue;
                const int o = lr * Wn + ww;
                acc += spm[o] * sw[kh * 7 + kw] + spa[o] * sw[49 + kh * 7 + kw];
            }
        }
        ssc[p] = 1.f / (1.f + expf(-acc));
    }
    __syncthreads();

    // Multiply: 16 channels x 16 rows x 64 cols. Thread t owns float4 #t of
    // the 256-float4 stripe within each channel plane; scale loaded from LDS
    // ONCE into registers, reused across all 16 channels.
    const float4 s = ((const float4*)ssc)[tid];

    const size_t base = (size_t)b * (CHW / 4)
                      + (size_t)(cg * CGRP) * HW4
                      + (size_t)stripe * (ROWS * Wn / 4) + tid;
    const float4* x4 = (const float4*)x;
    float4* o4 = (float4*)out;

    #pragma unroll 4
    for (int ch = 0; ch < CGRP; ++ch) {
        const size_t i4 = base + (size_t)ch * HW4;
        const float4 v = x4[i4];
        float4 o;
        o.x = v.x * s.x; o.y = v.y * s.y;
        o.z = v.z * s.z; o.w = v.w * s.w;
        o4[i4] = o;
    }
}

extern "C" void kernel_launch(void* const* d_in, const int* in_sizes, int n_in,
                              void* d_out, int out_size, void* d_ws, size_t ws_size,
                              hipStream_t stream) {
    const float* x = (const float*)d_in[0];
    const float* w = (const float*)d_in[1];
    float* out = (float*)d_out;

    // Workspace layout (floats): pmax[NPOS] | pavg[NPOS]  = 1 MB
    float* pmax = (float*)d_ws;
    float* pavg = pmax + NPOS;

    // Pass 1: channel max/mean. 512 blocks x 256 thr (4 waves, 64-ch chunks).
    reduce_k<<<NPOS4 / 64, 256, 0, stream>>>(x, pmax, pavg);

    // Pass 2: fused conv + sigmoid + multiply. 2048 blocks x 256 thr.
    convmul_k<<<Bn * NSTR * NCG, 256, 0, stream>>>(x, pmax, pavg, w, out);
}

// Round 5
// 248.498 us; speedup vs baseline: 1.1166x; 1.1166x over previous
//
#include <hip/hip_runtime.h>
#include <math.h>

// Problem constants (fixed by the reference)
constexpr int Bn  = 32;
constexpr int Cn  = 256;
constexpr int Hn  = 64;
constexpr int Wn  = 64;
constexpr int HW  = Hn * Wn;        // 4096
constexpr int CHW = Cn * HW;        // 1048576
constexpr int HW4 = HW / 4;         // 1024 float4 per (b,c) plane
constexpr int NPOS  = Bn * HW;      // 131072 spatial positions
constexpr int NPOS4 = NPOS / 4;     // 32768 float4 positions

// convmul tiling: block = (batch, 4-row stripe). 512 blocks, no redundancy.
constexpr int CM_ROWS  = 4;                  // rows per block
constexpr int CM_LR    = CM_ROWS + 6;        // 10 LDS rows (3-row halo each side)
constexpr int CM_LC    = 72;                 // 64 + 3+3 col halo, padded to 72
constexpr int CM_GRID  = NPOS4 / 64;         // 512 blocks (256 positions each)

typedef float f4_t __attribute__((ext_vector_type(4)));

// -------------------------------------------------------------------------
// Kernel 1: channel-wise max + mean. (round-0 version, byte-identical: the
// best-measured artifact. Round-3's 512-thread variant regressed.)
// Block = 256 threads = 4 waves. Wave `chunk` reduces channels
// [chunk*64, chunk*64+64) for 64 consecutive float4 spatial positions.
// Each load: 64 lanes x 16 B contiguous = 1 KiB coalesced.
// NOTE: cooperative grid.sync fusion is structurally dead on MI355X
// (rounds 1-2: sync spin ~70-250us/barrier, scales with block count).
// Separate dispatches win; L3 keeps x (134 MB < 256 MB) resident between
// kernel 1 and kernel 2.
// -------------------------------------------------------------------------
__global__ __launch_bounds__(256) void reduce_k(const float* __restrict__ x,
                                                float* __restrict__ pmax,
                                                float* __restrict__ pavg) {
    __shared__ float4 smax[4][64];
    __shared__ float4 ssum[4][64];

    const int lane  = threadIdx.x & 63;
    const int chunk = threadIdx.x >> 6;           // 0..3 (wave id)
    const int pos4  = blockIdx.x * 64 + lane;     // global float4 position
    const int b     = pos4 >> 10;                 // / HW4 (block never straddles b)
    const int sp4   = pos4 & (HW4 - 1);

    const float4* xp = (const float4*)x + (size_t)b * (CHW / 4)
                       + (size_t)(chunk * 64) * HW4 + sp4;

    float4 mx = make_float4(-INFINITY, -INFINITY, -INFINITY, -INFINITY);
    float4 sm = make_float4(0.f, 0.f, 0.f, 0.f);

    #pragma unroll 8
    for (int c = 0; c < 64; ++c) {
        float4 v = xp[(size_t)c * HW4];
        mx.x = fmaxf(mx.x, v.x); mx.y = fmaxf(mx.y, v.y);
        mx.z = fmaxf(mx.z, v.z); mx.w = fmaxf(mx.w, v.w);
        sm.x += v.x; sm.y += v.y; sm.z += v.z; sm.w += v.w;
    }

    smax[chunk][lane] = mx;
    ssum[chunk][lane] = sm;
    __syncthreads();

    if (chunk == 0) {
        float4 M = smax[0][lane];
        float4 S = ssum[0][lane];
        #pragma unroll
        for (int k = 1; k < 4; ++k) {
            float4 m2 = smax[k][lane];
            float4 s2 = ssum[k][lane];
            M.x = fmaxf(M.x, m2.x); M.y = fmaxf(M.y, m2.y);
            M.z = fmaxf(M.z, m2.z); M.w = fmaxf(M.w, m2.w);
            S.x += s2.x; S.y += s2.y; S.z += s2.z; S.w += s2.w;
        }
        const float inv = 1.0f / (float)Cn;
        float4 A = make_float4(S.x * inv, S.y * inv, S.z * inv, S.w * inv);
        ((float4*)pmax)[pos4] = M;
        ((float4*)pavg)[pos4] = A;
    }
}

// -------------------------------------------------------------------------
// Kernel 2: fused 7x7 conv + sigmoid + broadcast multiply, ZERO redundancy.
// Block = (batch b, 4-row stripe): 512 blocks x 256 threads (2 blocks/CU).
//   1. Stage pmax/pavg halo window (10 rows x 70 cols, zero-padded) into
//      LDS [10][72] -> conv becomes branchless.
//   2. Each thread computes conv+sigmoid for its ONE spatial position
//      (98 FMA, LDS operands; wave lanes read same-row consecutive cols ->
//      conflict-free). Total LDS conv traffic 103 MB ~ 1.5 us (r4's
//      16x-redundant version was 822 MB ~ 12 us -- the regression source).
//   3. Wave w streams channels [w*64, w*64+64): lane's float4 scale lives
//      in REGISTERS for all 64 iterations; 1 KiB coalesced per load instr.
// out stores are nontemporal: never re-read, and x+out (268 MB) > L3
// (256 MB) -- don't let out evict x mid-pass.
// -------------------------------------------------------------------------
__global__ __launch_bounds__(256) void convmul_k(const float* __restrict__ x,
                                                 const float* __restrict__ pmax,
                                                 const float* __restrict__ pavg,
                                                 const float* __restrict__ w,
                                                 float* __restrict__ out) {
    __shared__ float spm[CM_LR][CM_LC];   // pooled-max window (zero-padded)
    __shared__ float spa[CM_LR][CM_LC];   // pooled-avg window
    __shared__ float ssc[256];            // scale for the block's 256 positions
    __shared__ float sw[98];

    const int tid = threadIdx.x;
    const int bid = blockIdx.x;
    const int b   = bid >> 4;             // batch
    const int rg  = bid & 15;             // row-group: rows rg*4 .. rg*4+3
    const int row0 = rg * CM_ROWS;

    if (tid < 98) sw[tid] = w[tid];

    // ---- Stage halo window (rows row0-3..row0+6, cols -3..68; OOB -> 0) --
    const float* pm = pmax + b * HW;
    const float* pa = pavg + b * HW;
    for (int i = tid; i < CM_LR * CM_LC; i += 256) {
        const int lr = i / CM_LC;
        const int lc = i % CM_LC;
        const int gh = row0 - 3 + lr;
        const int gw = lc - 3;
        const bool ok = (gh >= 0) && (gh < Hn) && (gw >= 0) && (gw < Wn);
        const float vm = ok ? pm[gh * Wn + gw] : 0.f;
        const float va = ok ? pa[gh * Wn + gw] : 0.f;
        spm[lr][lc] = vm;
        spa[lr][lc] = va;
    }
    __syncthreads();

    // ---- Conv + sigmoid: one position per thread, branchless ------------
    {
        const int hl  = tid >> 6;         // local row 0..3 (== wave id)
        const int col = tid & 63;
        float acc = 0.f;
        #pragma unroll
        for (int kh = 0; kh < 7; ++kh) {
            #pragma unroll
            for (int kw = 0; kw < 7; ++kw) {
                acc += spm[hl + kh][col + kw] * sw[kh * 7 + kw]
                     + spa[hl + kh][col + kw] * sw[49 + kh * 7 + kw];
            }
        }
        ssc[tid] = 1.f / (1.f + expf(-acc));
    }
    __syncthreads();

    // ---- Stream: wave w covers channels [w*64, w*64+64) -----------------
    const int wv   = tid >> 6;
    const int lane = tid & 63;
    const int sp4  = rg * 64 + lane;      // float4 position within the plane

    const float4 s = ((const float4*)ssc)[lane];   // scale for lane's 4 cols

    const float4* x4 = (const float4*)x;
    float4* o4 = (float4*)out;

    size_t idx = (size_t)b * (CHW / 4) + (size_t)(wv * 64) * HW4 + sp4;
    #pragma unroll 4
    for (int k = 0; k < 64; ++k, idx += HW4) {
        const float4 v = x4[idx];
        f4_t o;
        o.x = v.x * s.x; o.y = v.y * s.y;
        o.z = v.z * s.z; o.w = v.w * s.w;
        __builtin_nontemporal_store(o, (f4_t*)&o4[idx]);
    }
}

extern "C" void kernel_launch(void* const* d_in, const int* in_sizes, int n_in,
                              void* d_out, int out_size, void* d_ws, size_t ws_size,
                              hipStream_t stream) {
    const float* x = (const float*)d_in[0];
    const float* w = (const float*)d_in[1];
    float* out = (float*)d_out;

    // Workspace layout (floats): pmax[NPOS] | pavg[NPOS]  = 1 MB
    float* pmax = (float*)d_ws;
    float* pavg = pmax + NPOS;

    // Pass 1: channel max/mean. 512 blocks x 256 thr (4 waves, 64-ch chunks).
    reduce_k<<<NPOS4 / 64, 256, 0, stream>>>(x, pmax, pavg);

    // Pass 2: fused conv + sigmoid + multiply. 512 blocks x 256 thr.
    convmul_k<<<CM_GRID, 256, 0, stream>>>(x, pmax, pavg, w, out);
}